// Round 1
// baseline (3848.370 us; speedup 1.0000x reference)
//
#include <hip/hip_runtime.h>
#include <hip/hip_bf16.h>

// HybridAttention (B=8,H=W=128,C=256, heads=8, levels [(16,8),(8,4)])
// fp32 baseline: everything decomposed into 5 GEMM modes + LN + 2 attn kernels.
//
// GEMM modes:
//  0 QLIN : q[131072,256]  = x[131072,256] @ q_w^T
//  1 CONV0: kv0[2048,512]  = im2col8x8s8(x)[2048,16384] @ w0^T + b0
//  2 CONV1: kv1[8192,512]  = im2col4x4s4(y0)[8192,4096] @ w1^T + b1
//  3 PROJ0: out[131072,256]= y0[131072,256] @ proj_w[:, :256]^T + pb
//  4 PROJ1: out          += y1[131072,256] @ proj_w[:, 256:]^T

#define BM 64
#define BN 64
#define BK 16

template<int MODE>
__global__ __launch_bounds__(256)
void gemm_k(const float* __restrict__ A, const float* __restrict__ W,
            const float* __restrict__ bias, float* __restrict__ C)
{
    constexpr int K = (MODE == 1) ? 16384 : (MODE == 2) ? 4096 : 256;
    __shared__ float As[BK][BM + 4];
    __shared__ float Bs[BK][BN + 4];

    const int tid = threadIdx.x;
    const int tx = tid & 15;        // 0..15 -> 4 cols each
    const int ty = tid >> 4;        // 0..15 -> 4 rows each
    const int lk = tid & 15;        // k-lane for loads
    const int lrow = tid >> 4;      // row-lane for loads (0..15, +16*r)
    const int bm = blockIdx.y * BM;
    const int bn = blockIdx.x * BN;

    float acc[4][4] = {};

    for (int k0 = 0; k0 < K; k0 += BK) {
        // ---- load A tile (64 x 16), k contiguous in memory for all modes ----
        #pragma unroll
        for (int r = 0; r < 4; ++r) {
            const int ml = lrow + 16 * r;
            const int m  = bm + ml;
            const int k  = k0 + lk;
            int addr;
            if constexpr (MODE == 0 || MODE == 3 || MODE == 4) {
                addr = m * 256 + k;
            } else if constexpr (MODE == 1) {
                // m -> (b, py, px) patch of 8x8 at stride 8 ; k = kyx*256 + c
                const int b = m >> 8, py = (m >> 4) & 15, px = m & 15;
                const int kyx = k >> 8, c = k & 255;
                const int ky = kyx >> 3, kx = kyx & 7;
                addr = ((b * 128 + py * 8 + ky) * 128 + px * 8 + kx) * 256 + c;
            } else { // MODE == 2
                const int b = m >> 10, py = (m >> 5) & 31, px = m & 31;
                const int kyx = k >> 8, c = k & 255;
                const int ky = kyx >> 2, kx = kyx & 3;
                addr = ((b * 128 + py * 4 + ky) * 128 + px * 4 + kx) * 256 + c;
            }
            As[lk][ml] = A[addr];
        }
        // ---- load B tile (16 x 64) from weights ----
        #pragma unroll
        for (int r = 0; r < 4; ++r) {
            const int nl = lrow + 16 * r;
            const int n  = bn + nl;
            const int k  = k0 + lk;
            int addr;
            if constexpr (MODE == 0) {
                addr = n * 256 + k;
            } else if constexpr (MODE == 1) {
                const int kyx = k >> 8, c = k & 255;
                addr = n * 16384 + c * 64 + kyx;
            } else if constexpr (MODE == 2) {
                const int kyx = k >> 8, c = k & 255;
                addr = n * 4096 + c * 16 + kyx;
            } else if constexpr (MODE == 3) {
                addr = n * 512 + k;
            } else { // MODE == 4
                addr = n * 512 + 256 + k;
            }
            Bs[lk][nl] = W[addr];
        }
        __syncthreads();

        #pragma unroll
        for (int kk = 0; kk < BK; ++kk) {
            const float4 av = *(const float4*)&As[kk][ty * 4];
            const float4 bv = *(const float4*)&Bs[kk][tx * 4];
            const float a[4] = {av.x, av.y, av.z, av.w};
            const float b[4] = {bv.x, bv.y, bv.z, bv.w};
            #pragma unroll
            for (int i = 0; i < 4; ++i)
                #pragma unroll
                for (int j = 0; j < 4; ++j)
                    acc[i][j] = fmaf(a[i], b[j], acc[i][j]);
        }
        __syncthreads();
    }

    // ---- epilogue ----
    #pragma unroll
    for (int i = 0; i < 4; ++i) {
        const int m = bm + ty * 4 + i;
        #pragma unroll
        for (int j = 0; j < 4; ++j) {
            const int n = bn + tx * 4 + j;
            float v = acc[i][j];
            if constexpr (MODE == 1 || MODE == 2 || MODE == 3) v += bias[n];
            if constexpr (MODE == 1 || MODE == 2) {
                C[m * 512 + n] = v;
            } else if constexpr (MODE == 4) {
                C[m * 256 + n] += v;
            } else {
                C[m * 256 + n] = v;
            }
        }
    }
}

// LayerNorm over 512 channels, one row per block (in-place). eps 1e-5, biased var.
__global__ __launch_bounds__(256)
void ln_k(float* __restrict__ buf, const float* __restrict__ g,
          const float* __restrict__ b)
{
    const int row = blockIdx.x;
    float* p = buf + (size_t)row * 512;
    const int t = threadIdx.x;
    const float v0 = p[t];
    const float v1 = p[t + 256];
    float s = v0 + v1;
    float sq = v0 * v0 + v1 * v1;

    __shared__ float red[8];
    const int lane = t & 63, wave = t >> 6;
    #pragma unroll
    for (int o = 1; o < 64; o <<= 1) {
        s  += __shfl_xor(s, o);
        sq += __shfl_xor(sq, o);
    }
    if (lane == 0) { red[wave] = s; red[wave + 4] = sq; }
    __syncthreads();
    const float S = red[0] + red[1] + red[2] + red[3];
    const float Q = red[4] + red[5] + red[6] + red[7];
    const float mean = S * (1.0f / 512.0f);
    const float var  = Q * (1.0f / 512.0f) - mean * mean;
    const float inv  = rsqrtf(var + 1e-5f);
    p[t]       = (v0 - mean) * inv * g[t] + b[t];
    p[t + 256] = (v1 - mean) * inv * g[t + 256] + b[t + 256];
}

// Level-0 attention: 4096 blocks = (b, n, wh, ww); 256 threads = queries.
__global__ __launch_bounds__(256)
void attn0_k(const float* __restrict__ q, const float* __restrict__ kv,
             float* __restrict__ y)
{
    const int bi = blockIdx.x;
    const int ww = bi & 7, wh = (bi >> 3) & 7, n = (bi >> 6) & 7, b = bi >> 9;

    __shared__ float ks[4][32], vs[4][32];
    const int t = threadIdx.x;
    if (t < 128) {
        const int s = t >> 5, d = t & 31;
        const int py = wh * 2 + (s >> 1), px = ww * 2 + (s & 1);
        ks[s][d] = kv[((b * 16 + py) * 16 + px) * 512 + n * 32 + d];
    } else {
        const int u = t - 128;
        const int s = u >> 5, d = u & 31;
        const int py = wh * 2 + (s >> 1), px = ww * 2 + (s & 1);
        vs[s][d] = kv[((b * 16 + py) * 16 + px) * 512 + 256 + n * 32 + d];
    }
    __syncthreads();

    const int p = t;
    const int row = wh * 16 + (p >> 4), col = ww * 16 + (p & 15);
    const int base = ((b * 128 + row) * 128 + col) * 256 + n * 32;

    float qr[32];
    #pragma unroll
    for (int i = 0; i < 8; ++i) {
        const float4 f = *(const float4*)(q + base + i * 4);
        qr[i * 4 + 0] = f.x; qr[i * 4 + 1] = f.y;
        qr[i * 4 + 2] = f.z; qr[i * 4 + 3] = f.w;
    }
    float sc[4];
    #pragma unroll
    for (int s = 0; s < 4; ++s) {
        float a = 0.f;
        #pragma unroll
        for (int d = 0; d < 32; ++d) a = fmaf(qr[d], ks[s][d], a);
        sc[s] = a * 0.17677669529663687f;
    }
    const float mx = fmaxf(fmaxf(sc[0], sc[1]), fmaxf(sc[2], sc[3]));
    float e[4], se = 0.f;
    #pragma unroll
    for (int s = 0; s < 4; ++s) { e[s] = __expf(sc[s] - mx); se += e[s]; }
    const float inv = 1.0f / se;
    #pragma unroll
    for (int s = 0; s < 4; ++s) e[s] *= inv;

    #pragma unroll
    for (int i = 0; i < 8; ++i) {
        float4 f;
        float* o = (float*)&f;
        #pragma unroll
        for (int j = 0; j < 4; ++j) {
            const int d = i * 4 + j;
            float a = 0.f;
            #pragma unroll
            for (int s = 0; s < 4; ++s) a = fmaf(e[s], vs[s][d], a);
            o[j] = a;
        }
        *(float4*)(y + base + i * 4) = f;
    }
}

// Level-1 attention: 16384 blocks = (b, n', wh', ww'); 64 threads = queries.
// q is gathered through the "faithful bug" reinterpretation of the level-0
// permuted q buffer, expressed directly against the linear q (B,H,W,C).
__global__ __launch_bounds__(64)
void attn1_k(const float* __restrict__ q, const float* __restrict__ kv,
             float* __restrict__ y)
{
    const int bi = blockIdx.x;
    const int wwp = bi & 15, whp = (bi >> 4) & 15, np = (bi >> 8) & 7, b = bi >> 11;

    __shared__ float ks[4][32], vs[4][32];
    const int t = threadIdx.x;
    #pragma unroll
    for (int r = 0; r < 4; ++r) {
        const int idx = r * 64 + t;     // 0..255
        const int s = (idx >> 5) & 3;
        const int d = idx & 31;
        const int py = whp * 2 + (s >> 1), px = wwp * 2 + (s & 1);
        const int base = ((b * 32 + py) * 32 + px) * 512;
        if (idx < 128) ks[s][d] = kv[base + np * 32 + d];
        else           vs[s][d] = kv[base + 256 + np * 32 + d];
    }
    __syncthreads();

    const int pp = t;                       // query index 0..63
    // bit-exact index map of: q0(B,nH,8,8,256,32) flat -> reshape(16,8,16,8,8,32)
    const int n0 = whp >> 1;
    const int wh = ((whp & 1) << 2) | ((pp >> 4) & 3);
    const int ww = (((pp >> 3) & 1) << 2) | (wwp >> 2);
    const int p0 = ((wwp & 3) << 6) | ((pp & 7) << 3) | np;
    const int row = wh * 16 + (p0 >> 4), col = ww * 16 + (p0 & 15);
    const int qbase = ((b * 128 + row) * 128 + col) * 256 + n0 * 32;

    float qr[32];
    #pragma unroll
    for (int i = 0; i < 8; ++i) {
        const float4 f = *(const float4*)(q + qbase + i * 4);
        qr[i * 4 + 0] = f.x; qr[i * 4 + 1] = f.y;
        qr[i * 4 + 2] = f.z; qr[i * 4 + 3] = f.w;
    }
    float sc[4];
    #pragma unroll
    for (int s = 0; s < 4; ++s) {
        float a = 0.f;
        #pragma unroll
        for (int d = 0; d < 32; ++d) a = fmaf(qr[d], ks[s][d], a);
        sc[s] = a * 0.17677669529663687f;
    }
    const float mx = fmaxf(fmaxf(sc[0], sc[1]), fmaxf(sc[2], sc[3]));
    float e[4], se = 0.f;
    #pragma unroll
    for (int s = 0; s < 4; ++s) { e[s] = __expf(sc[s] - mx); se += e[s]; }
    const float inv = 1.0f / se;
    #pragma unroll
    for (int s = 0; s < 4; ++s) e[s] *= inv;

    const int orow = whp * 8 + (pp >> 3), ocol = wwp * 8 + (pp & 7);
    const int obase = ((b * 128 + orow) * 128 + ocol) * 256 + np * 32;
    #pragma unroll
    for (int i = 0; i < 8; ++i) {
        float4 f;
        float* o = (float*)&f;
        #pragma unroll
        for (int j = 0; j < 4; ++j) {
            const int d = i * 4 + j;
            float a = 0.f;
            #pragma unroll
            for (int s = 0; s < 4; ++s) a = fmaf(e[s], vs[s][d], a);
            o[j] = a;
        }
        *(float4*)(y + obase + i * 4) = f;
    }
}

extern "C" void kernel_launch(void* const* d_in, const int* in_sizes, int n_in,
                              void* d_out, int out_size, void* d_ws, size_t ws_size,
                              hipStream_t stream)
{
    (void)in_sizes; (void)n_in; (void)out_size; (void)ws_size;
    const float* x   = (const float*)d_in[0];
    const float* qw  = (const float*)d_in[1];
    const float* cw0 = (const float*)d_in[2];
    const float* cb0 = (const float*)d_in[3];
    const float* g0  = (const float*)d_in[4];
    const float* b0  = (const float*)d_in[5];
    const float* cw1 = (const float*)d_in[6];
    const float* cb1 = (const float*)d_in[7];
    const float* g1  = (const float*)d_in[8];
    const float* b1  = (const float*)d_in[9];
    const float* pw  = (const float*)d_in[10];
    const float* pb  = (const float*)d_in[11];
    float* out = (float*)d_out;
    float* ws  = (float*)d_ws;

    // workspace layout (floats)
    float* q   = ws;                       // 33,554,432
    float* y0  = ws + 33554432;            // 33,554,432 (reused as y1 after PROJ0)
    float* kv0 = ws + 67108864;            //  1,048,576
    float* kv1 = ws + 68157440;            //  4,194,304
    // total 72,351,744 floats = ~290 MB

    const dim3 blk(256);
    gemm_k<0><<<dim3(4, 2048), blk, 0, stream>>>(x,  qw,  nullptr, q);    // q = x @ qw^T
    gemm_k<1><<<dim3(8, 32),   blk, 0, stream>>>(x,  cw0, cb0,     kv0);  // conv0 + bias
    ln_k<<<2048, 256, 0, stream>>>(kv0, g0, b0);                          // LN0
    attn0_k<<<4096, 256, 0, stream>>>(q, kv0, y0);                        // level-0 attn
    gemm_k<2><<<dim3(8, 128),  blk, 0, stream>>>(y0, cw1, cb1,     kv1);  // conv1 + bias
    ln_k<<<8192, 256, 0, stream>>>(kv1, g1, b1);                          // LN1
    gemm_k<3><<<dim3(4, 2048), blk, 0, stream>>>(y0, pw,  pb,      out);  // out  = y0 @ P0^T + pb
    attn1_k<<<16384, 64, 0, stream>>>(q, kv1, y0);                        // level-1 attn -> y1 (reuse y0)
    gemm_k<4><<<dim3(4, 2048), blk, 0, stream>>>(y0, pw,  nullptr, out);  // out += y1 @ P1^T
}

// Round 2
// 623.296 us; speedup vs baseline: 6.1742x; 6.1742x over previous
//
#include <hip/hip_runtime.h>
#include <hip/hip_bf16.h>

// HybridAttention — bf16 MFMA rewrite.
// GEMM modes (128x128 tile, BK=64, 4 waves, mfma_f32_16x16x32_bf16):
//  0 QLIN : qb[131072,256]  = xb @ wqb^T
//  1 CONV0: part[8][2048,512] = im2col8x8s8(xb) @ w0t^T   (split-K 8)
//  2 CONV1: part[2][8192,512] = im2col4x4s4(y0b) @ w1t^T  (split-K 2)
//  3 PROJ : out[131072,256] = [y0b|y1b] @ wpb^T + pb      (K=512 fused)
// redln_k: split-K reduce + bias + LayerNorm -> kv fp32.
// attn kernels read bf16 q, fp32 kv, write bf16 y.

typedef __attribute__((ext_vector_type(8))) short bf16x8;
typedef __attribute__((ext_vector_type(8))) unsigned short u16x8;
typedef __attribute__((ext_vector_type(4))) float f32x4;
typedef const unsigned int __attribute__((address_space(1)))* gptr_t;
typedef unsigned int __attribute__((address_space(3)))* lptr_t;

__device__ __forceinline__ unsigned short f2bf(float f) {
    unsigned int u = __float_as_uint(f);
    u = (u + 0x7FFFu + ((u >> 16) & 1u)) >> 16;   // RNE
    return (unsigned short)u;
}
__device__ __forceinline__ float bf2f(unsigned short h) {
    return __uint_as_float(((unsigned int)h) << 16);
}

// ---------------- fp32 -> bf16 elementwise (8/thread) ----------------
__global__ __launch_bounds__(256)
void cvt_k(const float* __restrict__ in, unsigned short* __restrict__ out, int n8)
{
    const int i = blockIdx.x * 256 + threadIdx.x;
    if (i >= n8) return;
    const float4 a = ((const float4*)in)[2 * i];
    const float4 b = ((const float4*)in)[2 * i + 1];
    u16x8 o;
    o[0] = f2bf(a.x); o[1] = f2bf(a.y); o[2] = f2bf(a.z); o[3] = f2bf(a.w);
    o[4] = f2bf(b.x); o[5] = f2bf(b.y); o[6] = f2bf(b.z); o[7] = f2bf(b.w);
    ((u16x8*)out)[i] = o;
}

// ---------------- conv weight transpose+cvt: [n][c][kyx] -> [n][kyx][c] ----------------
template<int KYX>
__global__ __launch_bounds__(256)
void wtrans_k(const float* __restrict__ in, unsigned short* __restrict__ out)
{
    const int c = threadIdx.x;          // 0..255
    const int kyx = blockIdx.x;         // 0..KYX-1
    const int n = blockIdx.y;           // 0..511
    const float v = in[((size_t)n * 256 + c) * KYX + kyx];
    out[((size_t)n * KYX + kyx) * 256 + c] = f2bf(v);
}

// ---------------- MFMA GEMM ----------------
// A-frag lane l: row = l&15, k = (l>>4)*8 + j (contiguous 8)  [m92/m97 pattern]
// B-frag lane l: col = l&15, k = (l>>4)*8 + j
// C/D  lane l reg r: row = (l>>4)*4 + r, col = l&15           [m89 verified]
// LDS tiles [128 rows][64 k] bf16, 16B-granule XOR swizzle: granule s at row r
// stored at s^(r&7); staged via global_load_lds with pre-swizzled SOURCE.
template<int MODE>
__global__ __launch_bounds__(256)
void mfma_gemm(const unsigned short* __restrict__ A, const unsigned short* __restrict__ A2,
               const unsigned short* __restrict__ Wt, const float* __restrict__ bias,
               float* __restrict__ Cf, unsigned short* __restrict__ Cb)
{
    constexpr int KT   = (MODE == 0) ? 4 : (MODE == 3) ? 8 : 32;           // BK=64 steps
    constexpr int LDB  = (MODE == 0) ? 256 : (MODE == 3) ? 512
                        : (MODE == 1) ? 16384 : 4096;                       // Wt row stride
    constexpr int MTOT = (MODE == 1) ? 2048 : (MODE == 2) ? 8192 : 131072;

    __shared__ unsigned short As[128 * 64];
    __shared__ unsigned short Bs[128 * 64];

    const int t = threadIdx.x;
    const int wid = t >> 6;
    const int lane = t & 63;
    const int lr = lane & 15;
    const int lg = lane >> 4;
    const int bm = blockIdx.y * 128;
    const int bn = blockIdx.x * 128;
    const int ksp = blockIdx.z;
    const int kbase = ksp * (KT * 64);

    f32x4 acc[4][4];
    #pragma unroll
    for (int m = 0; m < 4; ++m)
        #pragma unroll
        for (int n = 0; n < 4; ++n)
            acc[m][n] = f32x4{0.f, 0.f, 0.f, 0.f};

    for (int kt = 0; kt < KT; ++kt) {
        const int k0 = kbase + kt * 64;
        // ---- stage A tile: 1024 granules of 16B, 4 per thread ----
        #pragma unroll
        for (int i = 0; i < 4; ++i) {
            const int G = i * 256 + t;
            const int r = G >> 3;
            const int s = (G & 7) ^ (r & 7);      // pre-swizzled source granule
            const int k = k0 + s * 8;
            const unsigned short* src;
            if constexpr (MODE == 0) {
                src = A + (size_t)(bm + r) * 256 + k;
            } else if constexpr (MODE == 3) {
                const int m = bm + r;
                src = (k < 256) ? (A + (size_t)m * 256 + k)
                                : (A2 + (size_t)m * 256 + (k - 256));
            } else if constexpr (MODE == 1) {
                const int m = bm + r;
                const int b = m >> 8, py = (m >> 4) & 15, px = m & 15;
                const int kyx = k >> 8, c = k & 255;
                const int ky = kyx >> 3, kx = kyx & 7;
                src = A + ((size_t)((b * 128 + py * 8 + ky) * 128) + px * 8 + kx) * 256 + c;
            } else { // MODE == 2
                const int m = bm + r;
                const int b = m >> 10, py = (m >> 5) & 31, px = m & 31;
                const int kyx = k >> 8, c = k & 255;
                const int ky = kyx >> 2, kx = kyx & 3;
                src = A + ((size_t)((b * 128 + py * 4 + ky) * 128) + px * 4 + kx) * 256 + c;
            }
            __builtin_amdgcn_global_load_lds((gptr_t)(uintptr_t)src,
                (lptr_t)(uintptr_t)&As[(size_t)(i * 256 + wid * 64) * 8], 16, 0, 0);
        }
        // ---- stage B tile ----
        #pragma unroll
        for (int i = 0; i < 4; ++i) {
            const int G = i * 256 + t;
            const int r = G >> 3;
            const int s = (G & 7) ^ (r & 7);
            const int k = k0 + s * 8;
            const unsigned short* src = Wt + (size_t)(bn + r) * LDB + k;
            __builtin_amdgcn_global_load_lds((gptr_t)(uintptr_t)src,
                (lptr_t)(uintptr_t)&Bs[(size_t)(i * 256 + wid * 64) * 8], 16, 0, 0);
        }
        __syncthreads();   // compiler drains vmcnt before barrier

        const int wr = wid >> 1, wc = wid & 1;
        bf16x8 af[4][2], bf[4][2];
        #pragma unroll
        for (int m = 0; m < 4; ++m) {
            const int row = wr * 64 + m * 16 + lr;
            #pragma unroll
            for (int ks = 0; ks < 2; ++ks) {
                const int g = (ks * 4 + lg) ^ (row & 7);
                af[m][ks] = *(const bf16x8*)&As[row * 64 + g * 8];
            }
        }
        #pragma unroll
        for (int n = 0; n < 4; ++n) {
            const int row = wc * 64 + n * 16 + lr;
            #pragma unroll
            for (int ks = 0; ks < 2; ++ks) {
                const int g = (ks * 4 + lg) ^ (row & 7);
                bf[n][ks] = *(const bf16x8*)&Bs[row * 64 + g * 8];
            }
        }
        #pragma unroll
        for (int m = 0; m < 4; ++m)
            #pragma unroll
            for (int n = 0; n < 4; ++n)
                #pragma unroll
                for (int ks = 0; ks < 2; ++ks)
                    acc[m][n] = __builtin_amdgcn_mfma_f32_16x16x32_bf16(
                        af[m][ks], bf[n][ks], acc[m][n], 0, 0, 0);
        __syncthreads();
    }

    // ---- epilogue ----
    const int wr = wid >> 1, wc = wid & 1;
    #pragma unroll
    for (int m = 0; m < 4; ++m) {
        #pragma unroll
        for (int n = 0; n < 4; ++n) {
            const f32x4 v = acc[m][n];
            #pragma unroll
            for (int r = 0; r < 4; ++r) {
                const int gm = bm + wr * 64 + m * 16 + lg * 4 + r;
                const int gn = bn + wc * 64 + n * 16 + lr;
                if constexpr (MODE == 0) {
                    Cb[(size_t)gm * 256 + gn] = f2bf(v[r]);
                } else if constexpr (MODE == 3) {
                    Cf[(size_t)gm * 256 + gn] = v[r] + bias[gn];
                } else {
                    Cf[((size_t)ksp * MTOT + gm) * 512 + gn] = v[r];
                }
            }
        }
    }
}

// ---------------- split-K reduce + bias + LayerNorm ----------------
__global__ __launch_bounds__(256)
void redln_k(const float* __restrict__ p, const float* __restrict__ bias,
             const float* __restrict__ gg, const float* __restrict__ bb,
             float* __restrict__ kv, int M, int S)
{
    const int r = blockIdx.x, t = threadIdx.x;
    float v0 = bias[t], v1 = bias[t + 256];
    for (int s = 0; s < S; ++s) {
        const float* row = p + ((size_t)s * M + r) * 512;
        v0 += row[t];
        v1 += row[t + 256];
    }
    float sm = v0 + v1, sq = v0 * v0 + v1 * v1;
    __shared__ float red[8];
    const int lane = t & 63, wave = t >> 6;
    #pragma unroll
    for (int o = 1; o < 64; o <<= 1) {
        sm += __shfl_xor(sm, o);
        sq += __shfl_xor(sq, o);
    }
    if (lane == 0) { red[wave] = sm; red[wave + 4] = sq; }
    __syncthreads();
    const float S1 = red[0] + red[1] + red[2] + red[3];
    const float S2 = red[4] + red[5] + red[6] + red[7];
    const float mean = S1 * (1.0f / 512.0f);
    const float var  = S2 * (1.0f / 512.0f) - mean * mean;
    const float inv  = rsqrtf(var + 1e-5f);
    kv[(size_t)r * 512 + t]       = (v0 - mean) * inv * gg[t] + bb[t];
    kv[(size_t)r * 512 + t + 256] = (v1 - mean) * inv * gg[t + 256] + bb[t + 256];
}

// ---------------- Level-0 attention ----------------
__global__ __launch_bounds__(256)
void attn0_k(const unsigned short* __restrict__ q, const float* __restrict__ kv,
             unsigned short* __restrict__ y)
{
    const int bi = blockIdx.x;
    const int ww = bi & 7, wh = (bi >> 3) & 7, n = (bi >> 6) & 7, b = bi >> 9;

    __shared__ float ks[4][32], vs[4][32];
    const int t = threadIdx.x;
    if (t < 128) {
        const int s = t >> 5, d = t & 31;
        const int py = wh * 2 + (s >> 1), px = ww * 2 + (s & 1);
        ks[s][d] = kv[((b * 16 + py) * 16 + px) * 512 + n * 32 + d];
    } else {
        const int u = t - 128;
        const int s = u >> 5, d = u & 31;
        const int py = wh * 2 + (s >> 1), px = ww * 2 + (s & 1);
        vs[s][d] = kv[((b * 16 + py) * 16 + px) * 512 + 256 + n * 32 + d];
    }
    __syncthreads();

    const int p = t;
    const int row = wh * 16 + (p >> 4), col = ww * 16 + (p & 15);
    const size_t base = ((size_t)(b * 128 + row) * 128 + col) * 256 + n * 32;

    float qr[32];
    const u16x8* qp = (const u16x8*)(q + base);
    #pragma unroll
    for (int i = 0; i < 4; ++i) {
        const u16x8 v = qp[i];
        #pragma unroll
        for (int j = 0; j < 8; ++j) qr[i * 8 + j] = bf2f(v[j]);
    }
    float sc[4];
    #pragma unroll
    for (int s = 0; s < 4; ++s) {
        float a = 0.f;
        #pragma unroll
        for (int d = 0; d < 32; ++d) a = fmaf(qr[d], ks[s][d], a);
        sc[s] = a * 0.17677669529663687f;
    }
    const float mx = fmaxf(fmaxf(sc[0], sc[1]), fmaxf(sc[2], sc[3]));
    float e[4], se = 0.f;
    #pragma unroll
    for (int s = 0; s < 4; ++s) { e[s] = __expf(sc[s] - mx); se += e[s]; }
    const float inv = 1.0f / se;
    #pragma unroll
    for (int s = 0; s < 4; ++s) e[s] *= inv;

    #pragma unroll
    for (int i = 0; i < 4; ++i) {
        u16x8 o;
        #pragma unroll
        for (int j = 0; j < 8; ++j) {
            const int d = i * 8 + j;
            float a = 0.f;
            #pragma unroll
            for (int s = 0; s < 4; ++s) a = fmaf(e[s], vs[s][d], a);
            o[j] = f2bf(a);
        }
        ((u16x8*)(y + base))[i] = o;
    }
}

// ---------------- Level-1 attention (faithful-bug q gather) ----------------
__global__ __launch_bounds__(64)
void attn1_k(const unsigned short* __restrict__ q, const float* __restrict__ kv,
             unsigned short* __restrict__ y)
{
    const int bi = blockIdx.x;
    const int wwp = bi & 15, whp = (bi >> 4) & 15, np = (bi >> 8) & 7, b = bi >> 11;

    __shared__ float ks[4][32], vs[4][32];
    const int t = threadIdx.x;
    #pragma unroll
    for (int r = 0; r < 4; ++r) {
        const int idx = r * 64 + t;
        const int s = (idx >> 5) & 3;
        const int d = idx & 31;
        const int py = whp * 2 + (s >> 1), px = wwp * 2 + (s & 1);
        const int base = ((b * 32 + py) * 32 + px) * 512;
        if (idx < 128) ks[s][d] = kv[base + np * 32 + d];
        else           vs[s][d] = kv[base + 256 + np * 32 + d];
    }
    __syncthreads();

    const int pp = t;
    const int n0 = whp >> 1;
    const int wh = ((whp & 1) << 2) | ((pp >> 4) & 3);
    const int ww = (((pp >> 3) & 1) << 2) | (wwp >> 2);
    const int p0 = ((wwp & 3) << 6) | ((pp & 7) << 3) | np;
    const int row = wh * 16 + (p0 >> 4), col = ww * 16 + (p0 & 15);
    const size_t qbase = ((size_t)(b * 128 + row) * 128 + col) * 256 + n0 * 32;

    float qr[32];
    const u16x8* qp = (const u16x8*)(q + qbase);
    #pragma unroll
    for (int i = 0; i < 4; ++i) {
        const u16x8 v = qp[i];
        #pragma unroll
        for (int j = 0; j < 8; ++j) qr[i * 8 + j] = bf2f(v[j]);
    }
    float sc[4];
    #pragma unroll
    for (int s = 0; s < 4; ++s) {
        float a = 0.f;
        #pragma unroll
        for (int d = 0; d < 32; ++d) a = fmaf(qr[d], ks[s][d], a);
        sc[s] = a * 0.17677669529663687f;
    }
    const float mx = fmaxf(fmaxf(sc[0], sc[1]), fmaxf(sc[2], sc[3]));
    float e[4], se = 0.f;
    #pragma unroll
    for (int s = 0; s < 4; ++s) { e[s] = __expf(sc[s] - mx); se += e[s]; }
    const float inv = 1.0f / se;
    #pragma unroll
    for (int s = 0; s < 4; ++s) e[s] *= inv;

    const int orow = whp * 8 + (pp >> 3), ocol = wwp * 8 + (pp & 7);
    const size_t obase = ((size_t)(b * 128 + orow) * 128 + ocol) * 256 + np * 32;
    #pragma unroll
    for (int i = 0; i < 4; ++i) {
        u16x8 o;
        #pragma unroll
        for (int j = 0; j < 8; ++j) {
            const int d = i * 8 + j;
            float a = 0.f;
            #pragma unroll
            for (int s = 0; s < 4; ++s) a = fmaf(e[s], vs[s][d], a);
            o[j] = f2bf(a);
        }
        ((u16x8*)(y + obase))[i] = o;
    }
}

extern "C" void kernel_launch(void* const* d_in, const int* in_sizes, int n_in,
                              void* d_out, int out_size, void* d_ws, size_t ws_size,
                              hipStream_t stream)
{
    (void)in_sizes; (void)n_in; (void)out_size; (void)ws_size;
    const float* x   = (const float*)d_in[0];
    const float* qw  = (const float*)d_in[1];
    const float* cw0 = (const float*)d_in[2];
    const float* cb0 = (const float*)d_in[3];
    const float* g0  = (const float*)d_in[4];
    const float* b0  = (const float*)d_in[5];
    const float* cw1 = (const float*)d_in[6];
    const float* cb1 = (const float*)d_in[7];
    const float* g1  = (const float*)d_in[8];
    const float* b1  = (const float*)d_in[9];
    const float* pw  = (const float*)d_in[10];
    const float* pb  = (const float*)d_in[11];
    float* out = (float*)d_out;

    // ---- workspace layout (bytes), total 277,217,280 <= known-good 289 MB ----
    char* w = (char*)d_ws;
    unsigned short* xb  = (unsigned short*)(w + 0);           // 64 MB (reused as y1b)
    unsigned short* qb  = (unsigned short*)(w + 67108864);    // 64 MB
    unsigned short* y0b = (unsigned short*)(w + 134217728);   // 64 MB
    unsigned short* w0t = (unsigned short*)(w + 201326592);   // 16 MB
    unsigned short* w1t = (unsigned short*)(w + 218103808);   //  4 MB
    unsigned short* wqb = (unsigned short*)(w + 222298112);   // 128 KB
    unsigned short* wpb = (unsigned short*)(w + 222429184);   // 256 KB
    float*          kv0 = (float*)(w + 222691328);            //  4 MB
    float*          kv1 = (float*)(w + 226885632);            // 16 MB
    float*          part= (float*)(w + 243662848);            // 32 MB
    unsigned short* y1b = xb;

    cvt_k<<<16384, 256, 0, stream>>>(x, xb, 4194304);
    cvt_k<<<32,    256, 0, stream>>>(qw, wqb, 8192);
    cvt_k<<<64,    256, 0, stream>>>(pw, wpb, 16384);
    wtrans_k<64><<<dim3(64, 512), 256, 0, stream>>>(cw0, w0t);
    wtrans_k<16><<<dim3(16, 512), 256, 0, stream>>>(cw1, w1t);

    mfma_gemm<0><<<dim3(2, 1024),   256, 0, stream>>>(xb, nullptr, wqb, nullptr, nullptr, qb);
    mfma_gemm<1><<<dim3(4, 16, 8),  256, 0, stream>>>(xb, nullptr, w0t, nullptr, part, nullptr);
    redln_k<<<2048, 256, 0, stream>>>(part, cb0, g0, b0, kv0, 2048, 8);
    attn0_k<<<4096, 256, 0, stream>>>(qb, kv0, y0b);
    mfma_gemm<2><<<dim3(4, 64, 2),  256, 0, stream>>>(y0b, nullptr, w1t, nullptr, part, nullptr);
    redln_k<<<8192, 256, 0, stream>>>(part, cb1, g1, b1, kv1, 8192, 2);
    attn1_k<<<16384, 64, 0, stream>>>(qb, kv1, y1b);
    mfma_gemm<3><<<dim3(2, 1024),   256, 0, stream>>>(y0b, y1b, wpb, pb, out, nullptr);
}